// Round 1
// 464.045 us; speedup vs baseline: 1.0033x; 1.0033x over previous
//
#include <hip/hip_runtime.h>
#include <math.h>

// Problem constants (fixed shape)
#define B 256
#define W 512
#define F 512
#define N 512
#define GPART 4            // partial blocks per sample in kernel A
#define WPG (W / GPART)    // 128 words per A-block

// -----------------------------------------------------------------------------
// Kernel A: t partials.  grid = B*GPART, 512 threads (4 blocks/CU -> 32 waves/CU).
// Block (b,g) handles words [g*128, g*128+128).  Thread = (ws, f4):
//   ws = tid>>7 handles 32 words, f4 = tid&127 handles f = f4*4..f4*4+3 (float4).
// Writes t_part[b][g][f] = sum over this block's words of x[b,w,f]*wvec[w].
// UNCHANGED from previous round (HBM-streaming-bound, coalesced 1KB/instr).
// -----------------------------------------------------------------------------
__global__ __launch_bounds__(512) void tpart_kernel(
    const float* __restrict__ x,
    const float* __restrict__ wvec,
    float* __restrict__ t_part)
{
    const int blk = blockIdx.x;
    const int g   = blk & (GPART - 1);
    const int b   = blk >> 2;
    const int tid = threadIdx.x;
    const int ws  = tid >> 7;     // 0..3
    const int f4  = tid & 127;

    __shared__ float s_w[WPG];
    __shared__ float s_part[4][F];

    if (tid < WPG) s_w[tid] = wvec[g * WPG + tid];
    __syncthreads();

    const float* xb = x + (size_t)b * W * F + (size_t)(g * WPG + ws * 32) * F;
    float4 acc = make_float4(0.f, 0.f, 0.f, 0.f);
#pragma unroll 8
    for (int i = 0; i < 32; ++i) {
        const float4 xv = *(const float4*)(xb + (size_t)i * F + f4 * 4);
        const float  ww = s_w[ws * 32 + i];
        acc.x += xv.x * ww; acc.y += xv.y * ww;
        acc.z += xv.z * ww; acc.w += xv.w * ww;
    }
    *(float4*)&s_part[ws][f4 * 4] = acc;
    __syncthreads();

    const float t = (s_part[0][tid] + s_part[1][tid])
                  + (s_part[2][tid] + s_part[3][tid]);
    t_part[(size_t)blk * F + tid] = t;
}

// -----------------------------------------------------------------------------
// Kernel B: reduce t partials, Q = t@Wq, r = (1/sqrt(N)) * Wk@Q.
// grid = B, 512 threads.  Weights are L2-resident (1 MB each).
// UNCHANGED from previous round.
// -----------------------------------------------------------------------------
__global__ __launch_bounds__(512) void qr_kernel(
    const float* __restrict__ t_part,
    const float* __restrict__ Wq,
    const float* __restrict__ Wk,
    float* __restrict__ r_out)
{
    __shared__ float s_t[F];
    __shared__ float s_q[N];
    const int b = blockIdx.x, tid = threadIdx.x;

    float t = 0.f;
#pragma unroll
    for (int g = 0; g < GPART; ++g)
        t += t_part[((size_t)b * GPART + g) * F + tid];
    s_t[tid] = t;
    __syncthreads();

    // Q[tid] = sum_f t[f] * Wq[f,tid]; 4 independent accumulators
    float q0 = 0.f, q1 = 0.f, q2 = 0.f, q3 = 0.f;
#pragma unroll 4
    for (int f = 0; f < F; f += 4) {
        q0 += s_t[f + 0] * Wq[(size_t)(f + 0) * N + tid];
        q1 += s_t[f + 1] * Wq[(size_t)(f + 1) * N + tid];
        q2 += s_t[f + 2] * Wq[(size_t)(f + 2) * N + tid];
        q3 += s_t[f + 3] * Wq[(size_t)(f + 3) * N + tid];
    }
    s_q[tid] = (q0 + q1) + (q2 + q3);
    __syncthreads();

    // r[tid] = scale * sum_n Q[n] * Wk[tid,n]  (per-lane float4 row reads, L2)
    const float4* wkrow = (const float4*)(Wk + (size_t)tid * N);
    float r0 = 0.f, r1 = 0.f, r2 = 0.f, r3 = 0.f;
#pragma unroll 8
    for (int n4 = 0; n4 < N / 4; ++n4) {
        const float4 kv = wkrow[n4];
        const float4 qv = *(const float4*)&s_q[n4 * 4];
        r0 += kv.x * qv.x; r1 += kv.y * qv.y;
        r2 += kv.z * qv.z; r3 += kv.w * qv.w;
    }
    r_out[(size_t)b * F + tid] =
        ((r0 + r1) + (r2 + r3)) * 0.04419417382415922f;  // 1/sqrt(512)
}

// -----------------------------------------------------------------------------
// Kernel C v2: online softmax + c accumulation + out = c@Wv.
// grid = B, 512 threads (8 waves).  Wave wv handles words [wv*64, wv*64+64).
//
// REWRITE vs previous round: 8 words per batch instead of 2.
//  - 16 float4 loads issued per batch (4x deeper memory-level parallelism)
//  - 8 independent butterfly-reduce chains (48 shuffles become throughput-
//    bound, not a 6-deep DS-latency chain per word)
//  - ONE m/l/c rescale per 8 words instead of per word (exact same math:
//    m' = max(m, max_j d_j); c' = c*e^{m-m'} + sum_j e^{d_j-m'} * x_j)
// -----------------------------------------------------------------------------
__global__ __launch_bounds__(512) void attn_kernel(
    const float* __restrict__ x,
    const float* __restrict__ Wv,
    const float* __restrict__ r_in,
    float* __restrict__ out)
{
    const int b    = blockIdx.x;
    const int tid  = threadIdx.x;
    const int lane = tid & 63;
    const int wv   = tid >> 6;

    __shared__ float s_c[8][F];
    __shared__ float s_m[8];
    __shared__ float s_l[8];
    __shared__ float s_cf[F];

    const float* xb = x + (size_t)b * W * F;
    const float* rb = r_in + (size_t)b * F;
    const float4 r0 = *(const float4*)(rb + lane * 4);
    const float4 r1 = *(const float4*)(rb + 256 + lane * 4);

    float m = -INFINITY, l = 0.f;
    float4 c0 = make_float4(0.f, 0.f, 0.f, 0.f);
    float4 c1 = make_float4(0.f, 0.f, 0.f, 0.f);

    // 8 batches of 8 words each; unroll 2 -> 16 words in flight, ~190 VGPR
    // (stays under the 256 cap required for the 8-wave block; no spill)
#pragma unroll 2
    for (int t = 0; t < 8; ++t) {
        const float* row = xb + (size_t)(wv * 64 + t * 8) * F;

        float4 xa0[8], xa1[8];
#pragma unroll
        for (int j = 0; j < 8; ++j) {
            xa0[j] = *(const float4*)(row + (size_t)j * F + lane * 4);
            xa1[j] = *(const float4*)(row + (size_t)j * F + 256 + lane * 4);
        }

        // per-lane partial dots, 8 independent chains
        float d[8];
#pragma unroll
        for (int j = 0; j < 8; ++j) {
            d[j] = xa0[j].x * r0.x + xa0[j].y * r0.y
                 + xa0[j].z * r0.z + xa0[j].w * r0.w
                 + xa1[j].x * r1.x + xa1[j].y * r1.y
                 + xa1[j].z * r1.z + xa1[j].w * r1.w;
        }

        // 8-way-interleaved butterfly reduce across the wave
#pragma unroll
        for (int off = 32; off >= 1; off >>= 1) {
#pragma unroll
            for (int j = 0; j < 8; ++j)
                d[j] += __shfl_xor(d[j], off, 64);
        }

        // batched online-softmax update (one rescale per 8 words)
        const float mb = fmaxf(fmaxf(fmaxf(d[0], d[1]), fmaxf(d[2], d[3])),
                               fmaxf(fmaxf(d[4], d[5]), fmaxf(d[6], d[7])));
        const float mn = fmaxf(m, mb);
        const float sc = __expf(m - mn);   // m=-inf on first batch -> sc=0

        float p[8];
        float ps = 0.f;
#pragma unroll
        for (int j = 0; j < 8; ++j) {
            p[j] = __expf(d[j] - mn);
            ps += p[j];
        }
        l = l * sc + ps;

        float ax = c0.x * sc, ay = c0.y * sc, az = c0.z * sc, aw = c0.w * sc;
#pragma unroll
        for (int j = 0; j < 8; ++j) {
            ax += p[j] * xa0[j].x; ay += p[j] * xa0[j].y;
            az += p[j] * xa0[j].z; aw += p[j] * xa0[j].w;
        }
        c0 = make_float4(ax, ay, az, aw);

        ax = c1.x * sc; ay = c1.y * sc; az = c1.z * sc; aw = c1.w * sc;
#pragma unroll
        for (int j = 0; j < 8; ++j) {
            ax += p[j] * xa1[j].x; ay += p[j] * xa1[j].y;
            az += p[j] * xa1[j].z; aw += p[j] * xa1[j].w;
        }
        c1 = make_float4(ax, ay, az, aw);

        m = mn;
    }

    *(float4*)&s_c[wv][lane * 4]       = c0;
    *(float4*)&s_c[wv][256 + lane * 4] = c1;
    if (lane == 0) { s_m[wv] = m; s_l[wv] = l; }
    __syncthreads();

    float M = -INFINITY;
#pragma unroll
    for (int j = 0; j < 8; ++j) M = fmaxf(M, s_m[j]);
    float L = 0.f;
    float alpha[8];
#pragma unroll
    for (int j = 0; j < 8; ++j) {
        alpha[j] = __expf(s_m[j] - M);
        L += alpha[j] * s_l[j];
    }
    const float invL = 1.f / L;

    float cf = 0.f;
#pragma unroll
    for (int j = 0; j < 8; ++j) cf += alpha[j] * s_c[j][tid];
    s_cf[tid] = cf * invL;
    __syncthreads();

    // out[b,tid] = sum_f c[f] * Wv[f,tid]; 4 independent accumulators (L2-bound)
    float o0 = 0.f, o1 = 0.f, o2 = 0.f, o3 = 0.f;
#pragma unroll 4
    for (int f = 0; f < F; f += 4) {
        o0 += s_cf[f + 0] * Wv[(size_t)(f + 0) * N + tid];
        o1 += s_cf[f + 1] * Wv[(size_t)(f + 1) * N + tid];
        o2 += s_cf[f + 2] * Wv[(size_t)(f + 2) * N + tid];
        o3 += s_cf[f + 3] * Wv[(size_t)(f + 3) * N + tid];
    }
    out[(size_t)b * N + tid] = (o0 + o1) + (o2 + o3);
}

// -----------------------------------------------------------------------------
// Launcher.  ws layout: t_part = B*GPART*F floats (2 MB), then r = B*F (512 KB).
// -----------------------------------------------------------------------------
extern "C" void kernel_launch(void* const* d_in, const int* in_sizes, int n_in,
                              void* d_out, int out_size, void* d_ws, size_t ws_size,
                              hipStream_t stream)
{
    const float* x    = (const float*)d_in[0];
    const float* Wk   = (const float*)d_in[1];
    const float* Wq   = (const float*)d_in[2];
    const float* Wv   = (const float*)d_in[3];
    const float* wvec = (const float*)d_in[4];
    float* out    = (float*)d_out;
    float* t_part = (float*)d_ws;
    float* r      = t_part + (size_t)B * GPART * F;

    tpart_kernel<<<B * GPART, 512, 0, stream>>>(x, wvec, t_part);
    qr_kernel<<<B, 512, 0, stream>>>(t_part, Wq, Wk, r);
    attn_kernel<<<B, 512, 0, stream>>>(x, Wv, r, out);
}

// Round 2
// 455.040 us; speedup vs baseline: 1.0231x; 1.0198x over previous
//
#include <hip/hip_runtime.h>
#include <math.h>

// Problem constants (fixed shape)
#define B 256
#define W 512
#define F 512
#define N 512

// -----------------------------------------------------------------------------
// Fully fused per-sample kernel.  grid = B (1 block/CU), 512 threads (8 waves).
//
// Rationale (round-2 theory): the 3-kernel pipeline pays two launch/drain
// boundaries and a t_part HBM round-trip, while every sample's dataflow
//   t = x[b]^T @ wvec  ->  Q = t @ Wq  ->  r = Wk @ Q  ->  attn over x[b]
// is block-local.  Fused: phase-2 (latency-bound weight GEMVs) of each block
// overlaps phase-1/3 (BW-bound) of other blocks; x's second pass stays
// L3-warm (x = 268 MB ~= L3 capacity, just streamed by phase 1).
//
// Phase 1: t[f] = sum_w x[b,w,f]*wvec[w].  Wave wv owns words [wv*64, wv*64+64),
//          thread owns f-slices [lane*4, +4) and [256+lane*4, +4), batch-4 loads.
// Phase 2: Q[tid] = sum_f t[f]*Wq[f,tid];  r[tid] = scale * sum_n Wk[tid,n]*Q[n].
// Phase 3: identical to round-1 kernel C (8-word batches, one rescale/batch),
//          with r read from LDS instead of global.
// -----------------------------------------------------------------------------
__global__ __launch_bounds__(512) void fused_attn_kernel(
    const float* __restrict__ x,
    const float* __restrict__ Wq,
    const float* __restrict__ Wk,
    const float* __restrict__ Wv,
    const float* __restrict__ wvec,
    float* __restrict__ out)
{
    const int b    = blockIdx.x;
    const int tid  = threadIdx.x;
    const int lane = tid & 63;
    const int wv   = tid >> 6;

    __shared__ float s_w[W];       // staged wvec (phase 1 only)
    __shared__ float s_c[8][F];    // per-wave partials: t-partials (ph1), c-partials (ph3)
    __shared__ float s_t[F];
    __shared__ float s_q[N];
    __shared__ float s_r[F];
    __shared__ float s_m[8];
    __shared__ float s_l[8];
    __shared__ float s_cf[F];

    const float* xb = x + (size_t)b * W * F;

    // ---------------- Phase 1: t partials ----------------
    s_w[tid] = wvec[tid];          // W == blockDim == 512
    __syncthreads();

    {
        float4 t0 = make_float4(0.f, 0.f, 0.f, 0.f);
        float4 t1 = make_float4(0.f, 0.f, 0.f, 0.f);
#pragma unroll 2
        for (int i = 0; i < 64; i += 4) {
            const float* row = xb + (size_t)(wv * 64 + i) * F;
            float4 a0[4], a1[4];
#pragma unroll
            for (int j = 0; j < 4; ++j) {
                a0[j] = *(const float4*)(row + (size_t)j * F + lane * 4);
                a1[j] = *(const float4*)(row + (size_t)j * F + 256 + lane * 4);
            }
#pragma unroll
            for (int j = 0; j < 4; ++j) {
                const float ww = s_w[wv * 64 + i + j];
                t0.x += a0[j].x * ww; t0.y += a0[j].y * ww;
                t0.z += a0[j].z * ww; t0.w += a0[j].w * ww;
                t1.x += a1[j].x * ww; t1.y += a1[j].y * ww;
                t1.z += a1[j].z * ww; t1.w += a1[j].w * ww;
            }
        }
        *(float4*)&s_c[wv][lane * 4]       = t0;
        *(float4*)&s_c[wv][256 + lane * 4] = t1;
    }
    __syncthreads();

    {
        float t = 0.f;
#pragma unroll
        for (int j = 0; j < 8; ++j) t += s_c[j][tid];
        s_t[tid] = t;
    }
    __syncthreads();

    // ---------------- Phase 2: Q = t@Wq, r = scale * Wk@Q ----------------
    {
        float q0 = 0.f, q1 = 0.f, q2 = 0.f, q3 = 0.f;
#pragma unroll 4
        for (int f = 0; f < F; f += 4) {
            q0 += s_t[f + 0] * Wq[(size_t)(f + 0) * N + tid];
            q1 += s_t[f + 1] * Wq[(size_t)(f + 1) * N + tid];
            q2 += s_t[f + 2] * Wq[(size_t)(f + 2) * N + tid];
            q3 += s_t[f + 3] * Wq[(size_t)(f + 3) * N + tid];
        }
        s_q[tid] = (q0 + q1) + (q2 + q3);
    }
    __syncthreads();

    {
        const float4* wkrow = (const float4*)(Wk + (size_t)tid * N);
        float r0 = 0.f, r1 = 0.f, r2 = 0.f, r3 = 0.f;
#pragma unroll 8
        for (int n4 = 0; n4 < N / 4; ++n4) {
            const float4 kv = wkrow[n4];
            const float4 qv = *(const float4*)&s_q[n4 * 4];
            r0 += kv.x * qv.x; r1 += kv.y * qv.y;
            r2 += kv.z * qv.z; r3 += kv.w * qv.w;
        }
        s_r[tid] = ((r0 + r1) + (r2 + r3)) * 0.04419417382415922f;  // 1/sqrt(512)
    }
    __syncthreads();

    // ---------------- Phase 3: online softmax + c + out = c@Wv ----------------
    const float4 r0 = *(const float4*)&s_r[lane * 4];
    const float4 r1 = *(const float4*)&s_r[256 + lane * 4];

    float m = -INFINITY, l = 0.f;
    float4 c0 = make_float4(0.f, 0.f, 0.f, 0.f);
    float4 c1 = make_float4(0.f, 0.f, 0.f, 0.f);

    // 8 batches of 8 words; 16 float4 loads in flight, one m/l/c rescale per batch
#pragma unroll 2
    for (int t = 0; t < 8; ++t) {
        const float* row = xb + (size_t)(wv * 64 + t * 8) * F;

        float4 xa0[8], xa1[8];
#pragma unroll
        for (int j = 0; j < 8; ++j) {
            xa0[j] = *(const float4*)(row + (size_t)j * F + lane * 4);
            xa1[j] = *(const float4*)(row + (size_t)j * F + 256 + lane * 4);
        }

        float d[8];
#pragma unroll
        for (int j = 0; j < 8; ++j) {
            d[j] = xa0[j].x * r0.x + xa0[j].y * r0.y
                 + xa0[j].z * r0.z + xa0[j].w * r0.w
                 + xa1[j].x * r1.x + xa1[j].y * r1.y
                 + xa1[j].z * r1.z + xa1[j].w * r1.w;
        }

#pragma unroll
        for (int off = 32; off >= 1; off >>= 1) {
#pragma unroll
            for (int j = 0; j < 8; ++j)
                d[j] += __shfl_xor(d[j], off, 64);
        }

        const float mb = fmaxf(fmaxf(fmaxf(d[0], d[1]), fmaxf(d[2], d[3])),
                               fmaxf(fmaxf(d[4], d[5]), fmaxf(d[6], d[7])));
        const float mn = fmaxf(m, mb);
        const float sc = __expf(m - mn);   // m=-inf on first batch -> sc=0

        float p[8];
        float ps = 0.f;
#pragma unroll
        for (int j = 0; j < 8; ++j) {
            p[j] = __expf(d[j] - mn);
            ps += p[j];
        }
        l = l * sc + ps;

        float ax = c0.x * sc, ay = c0.y * sc, az = c0.z * sc, aw = c0.w * sc;
#pragma unroll
        for (int j = 0; j < 8; ++j) {
            ax += p[j] * xa0[j].x; ay += p[j] * xa0[j].y;
            az += p[j] * xa0[j].z; aw += p[j] * xa0[j].w;
        }
        c0 = make_float4(ax, ay, az, aw);

        ax = c1.x * sc; ay = c1.y * sc; az = c1.z * sc; aw = c1.w * sc;
#pragma unroll
        for (int j = 0; j < 8; ++j) {
            ax += p[j] * xa1[j].x; ay += p[j] * xa1[j].y;
            az += p[j] * xa1[j].z; aw += p[j] * xa1[j].w;
        }
        c1 = make_float4(ax, ay, az, aw);

        m = mn;
    }

    __syncthreads();  // s_c reuse: all waves done reading phase-1 partials
    *(float4*)&s_c[wv][lane * 4]       = c0;
    *(float4*)&s_c[wv][256 + lane * 4] = c1;
    if (lane == 0) { s_m[wv] = m; s_l[wv] = l; }
    __syncthreads();

    float M = -INFINITY;
#pragma unroll
    for (int j = 0; j < 8; ++j) M = fmaxf(M, s_m[j]);
    float L = 0.f;
    float alpha[8];
#pragma unroll
    for (int j = 0; j < 8; ++j) {
        alpha[j] = __expf(s_m[j] - M);
        L += alpha[j] * s_l[j];
    }
    const float invL = 1.f / L;

    float cf = 0.f;
#pragma unroll
    for (int j = 0; j < 8; ++j) cf += alpha[j] * s_c[j][tid];
    s_cf[tid] = cf * invL;
    __syncthreads();

    // out[b,tid] = sum_f c[f] * Wv[f,tid]
    float o0 = 0.f, o1 = 0.f, o2 = 0.f, o3 = 0.f;
#pragma unroll 4
    for (int f = 0; f < F; f += 4) {
        o0 += s_cf[f + 0] * Wv[(size_t)(f + 0) * N + tid];
        o1 += s_cf[f + 1] * Wv[(size_t)(f + 1) * N + tid];
        o2 += s_cf[f + 2] * Wv[(size_t)(f + 2) * N + tid];
        o3 += s_cf[f + 3] * Wv[(size_t)(f + 3) * N + tid];
    }
    out[(size_t)b * N + tid] = (o0 + o1) + (o2 + o3);
}

// -----------------------------------------------------------------------------
// Launcher.  Single fused launch; workspace unused.
// -----------------------------------------------------------------------------
extern "C" void kernel_launch(void* const* d_in, const int* in_sizes, int n_in,
                              void* d_out, int out_size, void* d_ws, size_t ws_size,
                              hipStream_t stream)
{
    const float* x    = (const float*)d_in[0];
    const float* Wk   = (const float*)d_in[1];
    const float* Wq   = (const float*)d_in[2];
    const float* Wv   = (const float*)d_in[3];
    const float* wvec = (const float*)d_in[4];
    float* out = (float*)d_out;

    fused_attn_kernel<<<B, 512, 0, stream>>>(x, Wq, Wk, Wv, wvec, out);
}

// Round 3
// 448.435 us; speedup vs baseline: 1.0382x; 1.0147x over previous
//
#include <hip/hip_runtime.h>
#include <math.h>

// Problem constants (fixed shape)
#define B 256
#define W 512
#define F 512
#define N 512
#define NWAVE 16   // 1024 threads = 16 waves = 4 waves/SIMD (2x round-2)

// -----------------------------------------------------------------------------
// Fully fused per-sample kernel, round 3: 1024-thread blocks.
//
// Round-2 evidence: 197 us, VALUBusy 9%, Occupancy 23%, warm iterations fetch
// ~0 HBM bytes (x L3-resident) yet same duration -> purely latency-bound at
// 2 waves/SIMD.  Fix: 16 waves/block (4/SIMD), halve per-wave serial work in
// phases 1/3, split phase-2 GEMVs across 1024 threads (256-term partials,
// combined in LDS).  VGPR capped at 128 via __launch_bounds__(1024, 4).
// -----------------------------------------------------------------------------
__global__ __launch_bounds__(1024, 4) void fused_attn_kernel(
    const float* __restrict__ x,
    const float* __restrict__ Wq,
    const float* __restrict__ Wk,
    const float* __restrict__ Wv,
    const float* __restrict__ wvec,
    float* __restrict__ out)
{
    const int b    = blockIdx.x;
    const int tid  = threadIdx.x;
    const int lane = tid & 63;
    const int wv   = tid >> 6;    // 0..15
    const int f5   = tid & 511;   // 0..511
    const int half = tid >> 9;    // 0..1

    __shared__ float s_w[W];           // staged wvec
    __shared__ float s_c[NWAVE][F];    // per-wave partials (t in ph1, c in ph3), 32 KB
    __shared__ float s_p2[2][F];       // half-split combine buffer (reused 4x)
    __shared__ float s_t[F];
    __shared__ float s_q[N];
    __shared__ float s_r[F];
    __shared__ float s_m[NWAVE];
    __shared__ float s_l[NWAVE];
    __shared__ float s_cf[F];

    const float* xb = x + (size_t)b * W * F;

    // ---------------- Phase 1: t[f] = sum_w x[w,f]*wvec[w] ----------------
    if (tid < W) s_w[tid] = wvec[tid];
    __syncthreads();

    {
        float4 t0 = make_float4(0.f, 0.f, 0.f, 0.f);
        float4 t1 = make_float4(0.f, 0.f, 0.f, 0.f);
        const float* base = xb + (size_t)(wv * 32) * F;
#pragma unroll 2
        for (int i = 0; i < 32; i += 4) {
            float4 a0[4], a1[4];
#pragma unroll
            for (int j = 0; j < 4; ++j) {
                a0[j] = *(const float4*)(base + (size_t)(i + j) * F + lane * 4);
                a1[j] = *(const float4*)(base + (size_t)(i + j) * F + 256 + lane * 4);
            }
#pragma unroll
            for (int j = 0; j < 4; ++j) {
                const float ww = s_w[wv * 32 + i + j];
                t0.x += a0[j].x * ww; t0.y += a0[j].y * ww;
                t0.z += a0[j].z * ww; t0.w += a0[j].w * ww;
                t1.x += a1[j].x * ww; t1.y += a1[j].y * ww;
                t1.z += a1[j].z * ww; t1.w += a1[j].w * ww;
            }
        }
        *(float4*)&s_c[wv][lane * 4]       = t0;
        *(float4*)&s_c[wv][256 + lane * 4] = t1;
    }
    __syncthreads();

    {   // two-stage 16-partial reduce
        float tp = 0.f;
#pragma unroll
        for (int j = 0; j < 8; ++j) tp += s_c[half * 8 + j][f5];
        s_p2[half][f5] = tp;
    }
    __syncthreads();
    if (tid < F) s_t[tid] = s_p2[0][tid] + s_p2[1][tid];
    __syncthreads();

    // ---------------- Phase 2: Q = t@Wq, r = scale * Wk@Q (half-split) ----
    {
        const int fb = half * 256;
        float q0 = 0.f, q1 = 0.f, q2 = 0.f, q3 = 0.f;
#pragma unroll 4
        for (int f = 0; f < 256; f += 4) {
            q0 += s_t[fb + f + 0] * Wq[(size_t)(fb + f + 0) * N + f5];
            q1 += s_t[fb + f + 1] * Wq[(size_t)(fb + f + 1) * N + f5];
            q2 += s_t[fb + f + 2] * Wq[(size_t)(fb + f + 2) * N + f5];
            q3 += s_t[fb + f + 3] * Wq[(size_t)(fb + f + 3) * N + f5];
        }
        s_p2[half][f5] = (q0 + q1) + (q2 + q3);
    }
    __syncthreads();
    if (tid < N) s_q[tid] = s_p2[0][tid] + s_p2[1][tid];
    __syncthreads();

    {
        const float4* wkrow = (const float4*)(Wk + (size_t)f5 * N + half * 256);
        const float4* qv4   = (const float4*)&s_q[half * 256];
        float r0 = 0.f, r1 = 0.f, r2 = 0.f, r3 = 0.f;
#pragma unroll 8
        for (int n4 = 0; n4 < 64; ++n4) {
            const float4 kv = wkrow[n4];
            const float4 qq = qv4[n4];
            r0 += kv.x * qq.x; r1 += kv.y * qq.y;
            r2 += kv.z * qq.z; r3 += kv.w * qq.w;
        }
        s_p2[half][f5] = (r0 + r1) + (r2 + r3);
    }
    __syncthreads();
    if (tid < F) s_r[tid] = (s_p2[0][tid] + s_p2[1][tid]) * 0.04419417382415922f;
    __syncthreads();

    // ---------------- Phase 3: online softmax + c accumulation ------------
    const float4 r0 = *(const float4*)&s_r[lane * 4];
    const float4 r1 = *(const float4*)&s_r[256 + lane * 4];

    float m = -INFINITY, l = 0.f;
    float4 c0 = make_float4(0.f, 0.f, 0.f, 0.f);
    float4 c1 = make_float4(0.f, 0.f, 0.f, 0.f);

    // wave wv owns words [wv*32, wv*32+32): 4 batches of 8 words
#pragma unroll 2
    for (int t = 0; t < 4; ++t) {
        const float* row = xb + (size_t)(wv * 32 + t * 8) * F;

        float4 xa0[8], xa1[8];
#pragma unroll
        for (int j = 0; j < 8; ++j) {
            xa0[j] = *(const float4*)(row + (size_t)j * F + lane * 4);
            xa1[j] = *(const float4*)(row + (size_t)j * F + 256 + lane * 4);
        }

        float d[8];
#pragma unroll
        for (int j = 0; j < 8; ++j) {
            d[j] = xa0[j].x * r0.x + xa0[j].y * r0.y
                 + xa0[j].z * r0.z + xa0[j].w * r0.w
                 + xa1[j].x * r1.x + xa1[j].y * r1.y
                 + xa1[j].z * r1.z + xa1[j].w * r1.w;
        }

#pragma unroll
        for (int off = 32; off >= 1; off >>= 1) {
#pragma unroll
            for (int j = 0; j < 8; ++j)
                d[j] += __shfl_xor(d[j], off, 64);
        }

        const float mb = fmaxf(fmaxf(fmaxf(d[0], d[1]), fmaxf(d[2], d[3])),
                               fmaxf(fmaxf(d[4], d[5]), fmaxf(d[6], d[7])));
        const float mn = fmaxf(m, mb);
        const float sc = __expf(m - mn);   // m=-inf on first batch -> sc=0

        float p[8];
        float ps = 0.f;
#pragma unroll
        for (int j = 0; j < 8; ++j) {
            p[j] = __expf(d[j] - mn);
            ps += p[j];
        }
        l = l * sc + ps;

        float ax = c0.x * sc, ay = c0.y * sc, az = c0.z * sc, aw = c0.w * sc;
#pragma unroll
        for (int j = 0; j < 8; ++j) {
            ax += p[j] * xa0[j].x; ay += p[j] * xa0[j].y;
            az += p[j] * xa0[j].z; aw += p[j] * xa0[j].w;
        }
        c0 = make_float4(ax, ay, az, aw);

        ax = c1.x * sc; ay = c1.y * sc; az = c1.z * sc; aw = c1.w * sc;
#pragma unroll
        for (int j = 0; j < 8; ++j) {
            ax += p[j] * xa1[j].x; ay += p[j] * xa1[j].y;
            az += p[j] * xa1[j].z; aw += p[j] * xa1[j].w;
        }
        c1 = make_float4(ax, ay, az, aw);

        m = mn;
    }

    *(float4*)&s_c[wv][lane * 4]       = c0;
    *(float4*)&s_c[wv][256 + lane * 4] = c1;
    if (lane == 0) { s_m[wv] = m; s_l[wv] = l; }
    __syncthreads();

    // ---------------- Merge 16 waves + normalize --------------------------
    float M = -INFINITY;
#pragma unroll
    for (int j = 0; j < NWAVE; ++j) M = fmaxf(M, s_m[j]);
    float L = 0.f;
    float alpha[NWAVE];
#pragma unroll
    for (int j = 0; j < NWAVE; ++j) {
        alpha[j] = __expf(s_m[j] - M);
        L += alpha[j] * s_l[j];
    }
    const float invL = 1.f / L;

    {   // two-stage alpha-weighted combine of 16 c-partials
        float cp = 0.f;
#pragma unroll
        for (int j = 0; j < 8; ++j) cp += alpha[half * 8 + j] * s_c[half * 8 + j][f5];
        s_p2[half][f5] = cp;
    }
    __syncthreads();
    if (tid < F) s_cf[tid] = (s_p2[0][tid] + s_p2[1][tid]) * invL;
    __syncthreads();

    // ---------------- out = cf @ Wv (half-split GEMV) ---------------------
    {
        const int fb = half * 256;
        float o0 = 0.f, o1 = 0.f, o2 = 0.f, o3 = 0.f;
#pragma unroll 4
        for (int f = 0; f < 256; f += 4) {
            o0 += s_cf[fb + f + 0] * Wv[(size_t)(fb + f + 0) * N + f5];
            o1 += s_cf[fb + f + 1] * Wv[(size_t)(fb + f + 1) * N + f5];
            o2 += s_cf[fb + f + 2] * Wv[(size_t)(fb + f + 2) * N + f5];
            o3 += s_cf[fb + f + 3] * Wv[(size_t)(fb + f + 3) * N + f5];
        }
        s_p2[half][f5] = (o0 + o1) + (o2 + o3);
    }
    __syncthreads();
    if (tid < N) out[(size_t)b * N + tid] = s_p2[0][tid] + s_p2[1][tid];
}

// -----------------------------------------------------------------------------
// Launcher.  Single fused launch; workspace unused.
// -----------------------------------------------------------------------------
extern "C" void kernel_launch(void* const* d_in, const int* in_sizes, int n_in,
                              void* d_out, int out_size, void* d_ws, size_t ws_size,
                              hipStream_t stream)
{
    const float* x    = (const float*)d_in[0];
    const float* Wk   = (const float*)d_in[1];
    const float* Wq   = (const float*)d_in[2];
    const float* Wv   = (const float*)d_in[3];
    const float* wvec = (const float*)d_in[4];
    float* out = (float*)d_out;

    fused_attn_kernel<<<B, 1024, 0, stream>>>(x, Wq, Wk, Wv, wvec, out);
}